// Round 2
// baseline (212.646 us; speedup 1.0000x reference)
//
#include <hip/hip_runtime.h>
#include <hip/hip_bf16.h>
#include <stdint.h>

// BigBird block-sparse attention, MI355X bf16-MFMA implementation.
// B=2 S=4096 H=768 NH=12 D=64 BLK=64 NB=64 R=3
#define NHD 12
#define SLEN 4096
#define DH 64
#define NBLK 64
#define HDIM 768
#define PEN -10000.0f

typedef __bf16 bf16x8 __attribute__((ext_vector_type(8)));
typedef float f32x4 __attribute__((ext_vector_type(4)));
typedef unsigned short u16x8 __attribute__((ext_vector_type(8)));

__device__ __forceinline__ unsigned short f2bf(float x) {
    union { float f; unsigned u; } v; v.f = x;
    unsigned r = v.u + 0x7fffu + ((v.u >> 16) & 1u);   // RNE
    return (unsigned short)(r >> 16);
}

// ---------------- cast hidden_states f32 -> bf16 ----------------
__global__ void k_cast_hs(const float* __restrict__ in, unsigned short* __restrict__ out, int n8) {
    int i = blockIdx.x * blockDim.x + threadIdx.x;
    if (i >= n8) return;
    const float4* p = (const float4*)in + (size_t)i * 2;
    float4 a = p[0], b = p[1];
    u16x8 o;
    o[0]=f2bf(a.x); o[1]=f2bf(a.y); o[2]=f2bf(a.z); o[3]=f2bf(a.w);
    o[4]=f2bf(b.x); o[5]=f2bf(b.y); o[6]=f2bf(b.z); o[7]=f2bf(b.w);
    ((u16x8*)out)[i] = o;
}

// ---------------- W (k,n) f32 -> Wt (n,k) bf16 ----------------
__global__ void k_wt(const float* __restrict__ Wq, const float* __restrict__ Wk,
                     const float* __restrict__ Wv, unsigned short* __restrict__ wt) {
    const float* W = blockIdx.z == 0 ? Wq : (blockIdx.z == 1 ? Wk : Wv);
    unsigned short* out = wt + (size_t)blockIdx.z * HDIM * HDIM;
    __shared__ float tile[64][65];
    int t = threadIdx.x;
    int k0 = blockIdx.x * 64, n0 = blockIdx.y * 64;
    int r = t >> 2, c4 = t & 3;
#pragma unroll
    for (int j = 0; j < 16; j += 4) {
        float4 v = *(const float4*)&W[(size_t)(k0 + r) * HDIM + n0 + c4 * 16 + j];
        tile[r][c4*16+j+0] = v.x; tile[r][c4*16+j+1] = v.y;
        tile[r][c4*16+j+2] = v.z; tile[r][c4*16+j+3] = v.w;
    }
    __syncthreads();
    u16x8 o0, o1;
#pragma unroll
    for (int j = 0; j < 8; ++j) o0[j] = f2bf(tile[c4*16 + j][r]);
#pragma unroll
    for (int j = 0; j < 8; ++j) o1[j] = f2bf(tile[c4*16 + 8 + j][r]);
    *(u16x8*)&out[(size_t)(n0 + r) * HDIM + k0 + c4*16]     = o0;
    *(u16x8*)&out[(size_t)(n0 + r) * HDIM + k0 + c4*16 + 8] = o1;
}

// ---------------- projection GEMM: (8192x768)x(768x768) bf16 MFMA ----------------
// out layout (B,NH,S,D) bf16.  z selects {Q,K,V}.
__global__ __launch_bounds__(256) void k_proj(const unsigned short* __restrict__ hsb,
                                              const unsigned short* __restrict__ wtb,
                                              unsigned short* __restrict__ qkv) {
    __shared__ unsigned short As[128][72];
    __shared__ unsigned short Bs[128][72];
    const unsigned short* Bw = wtb + (size_t)blockIdx.z * HDIM * HDIM;
    unsigned short* out = qkv + (size_t)blockIdx.z * (2u * NHD * SLEN * DH);
    int m0 = blockIdx.x * 128, n0 = blockIdx.y * 128;
    int t = threadIdx.x;
    int w = t >> 6, l = t & 63, g = l >> 4, c = l & 15;
    int wm = w >> 1, wn = w & 1;
    int sr = t >> 1, sh = (t & 1) * 32;
    f32x4 acc[4][4];
#pragma unroll
    for (int i = 0; i < 4; ++i)
#pragma unroll
        for (int j = 0; j < 4; ++j) acc[i][j] = (f32x4){0.f,0.f,0.f,0.f};

    for (int kt = 0; kt < HDIM; kt += 64) {
        __syncthreads();
#pragma unroll
        for (int j = 0; j < 4; ++j) {
            *(u16x8*)&As[sr][sh + 8*j] = *(const u16x8*)&hsb[(size_t)(m0 + sr) * HDIM + kt + sh + 8*j];
            *(u16x8*)&Bs[sr][sh + 8*j] = *(const u16x8*)&Bw[(size_t)(n0 + sr) * HDIM + kt + sh + 8*j];
        }
        __syncthreads();
#pragma unroll
        for (int ks = 0; ks < 2; ++ks) {
            bf16x8 af[4], bf_[4];
#pragma unroll
            for (int mt = 0; mt < 4; ++mt) af[mt]  = *(const bf16x8*)&As[64*wm + 16*mt + c][32*ks + 8*g];
#pragma unroll
            for (int nt = 0; nt < 4; ++nt) bf_[nt] = *(const bf16x8*)&Bs[64*wn + 16*nt + c][32*ks + 8*g];
#pragma unroll
            for (int mt = 0; mt < 4; ++mt)
#pragma unroll
                for (int nt = 0; nt < 4; ++nt)
                    acc[mt][nt] = __builtin_amdgcn_mfma_f32_16x16x32_bf16(af[mt], bf_[nt], acc[mt][nt], 0, 0, 0);
        }
    }
#pragma unroll
    for (int mt = 0; mt < 4; ++mt)
#pragma unroll
        for (int nt = 0; nt < 4; ++nt)
#pragma unroll
            for (int r2 = 0; r2 < 4; ++r2) {
                int m = m0 + 64*wm + 16*mt + 4*g + r2;
                int n = n0 + 64*wn + 16*nt + c;
                int bb = m >> 12, s = m & 4095;
                int hh = n >> 6,  d = n & 63;
                out[(((size_t)bb * NHD + hh) * SLEN + s) * DH + d] = f2bf(acc[mt][nt][r2]);
            }
}

// ---------------- V (bh,s,d) -> VT (bh,d,s) bf16 ----------------
__global__ void k_vtrans(const unsigned short* __restrict__ v, unsigned short* __restrict__ vt) {
    __shared__ unsigned tile[64][65];
    int bh = blockIdx.y;
    int s0 = blockIdx.x * 64;
    int t = threadIdx.x;
    int r = t >> 2, c4 = t & 3;
    const unsigned short* vb = v + (size_t)bh * SLEN * DH;
#pragma unroll
    for (int jj = 0; jj < 16; jj += 8) {
        u16x8 x = *(const u16x8*)&vb[(size_t)(s0 + r) * DH + c4*16 + jj];
#pragma unroll
        for (int e = 0; e < 8; ++e) tile[r][c4*16 + jj + e] = x[e];
    }
    __syncthreads();
    unsigned short* vto = vt + (size_t)bh * DH * SLEN;
    int d = t >> 2;
    u16x8 o0, o1;
#pragma unroll
    for (int j = 0; j < 8; ++j) o0[j] = (unsigned short)tile[c4*16 + j][d];
#pragma unroll
    for (int j = 0; j < 8; ++j) o1[j] = (unsigned short)tile[c4*16 + 8 + j][d];
    *(u16x8*)&vto[(size_t)d * SLEN + s0 + c4*16]     = o0;
    *(u16x8*)&vto[(size_t)d * SLEN + s0 + c4*16 + 8] = o1;
}

// ---------------- unified block-sparse attention ----------------
// grid = B*NH*78.  tasks per (b,h): 0..7 first-row partials, 8 qblk1,
// 9..68 middle (qb=task-7), 69 qblk62, 70..77 last-row partials.
// 8 waves; wave w owns key-slot block kb[w] (64 keys).  S^T = K*Q^T, then
// in-register softmax, P->LDS (bf16), ctx = P*V^T.
__global__ __launch_bounds__(512) void k_attn(
    const unsigned short* __restrict__ Qb, const unsigned short* __restrict__ Kb,
    const unsigned short* __restrict__ VTb,
    const int* __restrict__ rand_attn,
    const float* __restrict__ band_mask, const float* __restrict__ from_mask,
    const float* __restrict__ to_mask, const float* __restrict__ fbm,
    const float* __restrict__ tbm,
    float* __restrict__ out, float* __restrict__ partials)
{
    __shared__ unsigned short Qs[64][72];
    __shared__ unsigned short Ps[64][520];
    __shared__ float red[8][64];
    __shared__ float Mf[64], Lf[64];

    int gid = blockIdx.x;
    int bh = gid / 78, task = gid - bh * 78;
    int b = bh / NHD, h = bh - b * NHD;
    int t = threadIdx.x;
    int w = t >> 6, l = t & 63, g = l >> 4, c = l & 15;

    int qb, mode = 0, pslot = 0, rrow = -1;
    int kb[8], kind[8];           // kind: 0=to_mask 1=band 2=rand 3=absent
    if (task < 8) {
        qb = 0; mode = 1; pslot = task;
#pragma unroll
        for (int j = 0; j < 8; ++j) { kb[j] = task * 8 + j; kind[j] = 0; }
    } else if (task == 8) {
        qb = 1; rrow = 0;
        kb[0]=0; kb[1]=1; kb[2]=2; kb[3]=63; kb[7]=-1;
        kind[0]=kind[1]=kind[2]=kind[3]=0; kind[4]=kind[5]=kind[6]=2; kind[7]=3;
    } else if (task < 69) {
        int lm = task - 9; qb = lm + 2; rrow = lm + 1;
        kb[0]=0; kb[1]=lm+1; kb[2]=lm+2; kb[3]=lm+3; kb[7]=63;
        kind[0]=0; kind[1]=kind[2]=kind[3]=1; kind[4]=kind[5]=kind[6]=2; kind[7]=0;
    } else if (task == 69) {
        qb = 62; rrow = 61;
        kb[0]=0; kb[1]=61; kb[2]=62; kb[3]=63; kb[7]=-1;
        kind[0]=kind[1]=kind[2]=kind[3]=0; kind[4]=kind[5]=kind[6]=2; kind[7]=3;
    } else {
        qb = 63; mode = 1; pslot = task - 70;
#pragma unroll
        for (int j = 0; j < 8; ++j) { kb[j] = pslot * 8 + j; kind[j] = 0; }
    }
    if (rrow >= 0) {
#pragma unroll
        for (int j = 0; j < 3; ++j)
            kb[4 + j] = rand_attn[((size_t)(b * NHD + h) * 62 + rrow) * 3 + j];
    }

    size_t bhoff = (size_t)bh * SLEN * DH;
    {   // stage Q block
        int r = t >> 3, cc = t & 7;
        *(u16x8*)&Qs[r][cc * 8] = *(const u16x8*)&Qb[bhoff + (size_t)(qb * 64 + r) * DH + cc * 8];
    }
    __syncthreads();

    // ---- S^T = K * Q^T  (wave w: its 64 keys x all 64 q) ----
    f32x4 acc[4][4];
#pragma unroll
    for (int i = 0; i < 4; ++i)
#pragma unroll
        for (int j = 0; j < 4; ++j) acc[i][j] = (f32x4){0.f,0.f,0.f,0.f};

    int myb = kb[w], mykind = kind[w];
    if (myb >= 0) {
        const unsigned short* Kp = Kb + bhoff + (size_t)myb * 64 * DH;
#pragma unroll
        for (int ks = 0; ks < 2; ++ks) {
            bf16x8 af[4], bq[4];
#pragma unroll
            for (int mt = 0; mt < 4; ++mt) af[mt] = *(const bf16x8*)&Kp[(16*mt + c) * DH + 32*ks + 8*g];
#pragma unroll
            for (int nt = 0; nt < 4; ++nt) bq[nt] = *(const bf16x8*)&Qs[16*nt + c][32*ks + 8*g];
#pragma unroll
            for (int mt = 0; mt < 4; ++mt)
#pragma unroll
                for (int nt = 0; nt < 4; ++nt)
                    acc[mt][nt] = __builtin_amdgcn_mfma_f32_16x16x32_bf16(af[mt], bq[nt], acc[mt][nt], 0, 0, 0);
        }
    }

    // ---- scale + penalties (value at (key=16mt+4g+r2, q=16nt+c)) ----
    if (myb < 0) {
#pragma unroll
        for (int mt = 0; mt < 4; ++mt)
#pragma unroll
            for (int nt = 0; nt < 4; ++nt)
#pragma unroll
                for (int r2 = 0; r2 < 4; ++r2) acc[mt][nt][r2] = -30000.f;
    } else {
        float aux[4][4];
        if (mykind == 0) {
#pragma unroll
            for (int mt = 0; mt < 4; ++mt)
#pragma unroll
                for (int r2 = 0; r2 < 4; ++r2)
                    aux[mt][r2] = to_mask[b * SLEN + myb * 64 + 16*mt + 4*g + r2];
        } else if (mykind == 2) {
#pragma unroll
            for (int mt = 0; mt < 4; ++mt)
#pragma unroll
                for (int r2 = 0; r2 < 4; ++r2)
                    aux[mt][r2] = tbm[(b * NBLK + myb) * 64 + 16*mt + 4*g + r2];
        }
        float fmq[4];
        if (mykind == 2) {
#pragma unroll
            for (int nt = 0; nt < 4; ++nt) fmq[nt] = fbm[(b * NBLK + qb) * 64 + 16*nt + c];
        }
#pragma unroll
        for (int mt = 0; mt < 4; ++mt)
#pragma unroll
            for (int nt = 0; nt < 4; ++nt)
#pragma unroll
                for (int r2 = 0; r2 < 4; ++r2) {
                    float x = acc[mt][nt][r2] * 0.125f;
                    float maskv;
                    if (mykind == 0) maskv = aux[mt][r2];
                    else if (mykind == 1) {
                        int slot = 64*w + 16*mt + 4*g + r2;     // 64..255
                        int q = 16*nt + c;
                        maskv = band_mask[(((size_t)b * 60 + (qb - 2)) * 64 + q) * 192 + (slot - 64)];
                    } else {
                        maskv = fmq[nt] * aux[mt][r2];
                    }
                    acc[mt][nt][r2] = x + (1.f - maskv) * PEN;
                }
    }

    // ---- softmax over 512 key-slots per q ----
    float Mq[4];
    {
        float mw[4];
#pragma unroll
        for (int nt = 0; nt < 4; ++nt) {
            float m = -1e30f;
#pragma unroll
            for (int mt = 0; mt < 4; ++mt)
#pragma unroll
                for (int r2 = 0; r2 < 4; ++r2) m = fmaxf(m, acc[mt][nt][r2]);
            m = fmaxf(m, __shfl_xor(m, 16));
            m = fmaxf(m, __shfl_xor(m, 32));
            mw[nt] = m;
        }
        if (l < 16) {
#pragma unroll
            for (int nt = 0; nt < 4; ++nt) red[w][16*nt + l] = mw[nt];
        }
        __syncthreads();
#pragma unroll
        for (int nt = 0; nt < 4; ++nt) {
            float m = -1e30f;
#pragma unroll
            for (int i = 0; i < 8; ++i) m = fmaxf(m, red[i][16*nt + c]);
            Mq[nt] = m;
        }
        __syncthreads();
    }
    {
        float sw[4];
#pragma unroll
        for (int nt = 0; nt < 4; ++nt) {
            float s = 0.f;
#pragma unroll
            for (int mt = 0; mt < 4; ++mt)
#pragma unroll
                for (int r2 = 0; r2 < 4; ++r2) {
                    float e = __expf(acc[mt][nt][r2] - Mq[nt]);
                    acc[mt][nt][r2] = e;
                    s += e;
                }
            s += __shfl_xor(s, 16);
            s += __shfl_xor(s, 32);
            sw[nt] = s;
        }
#pragma unroll
        for (int mt = 0; mt < 4; ++mt)
#pragma unroll
            for (int nt = 0; nt < 4; ++nt) {
                int q = 16*nt + c;
                int key = 64*w + 16*mt + 4*g;
                unsigned p01 = (unsigned)f2bf(acc[mt][nt][0]) | ((unsigned)f2bf(acc[mt][nt][1]) << 16);
                unsigned p23 = (unsigned)f2bf(acc[mt][nt][2]) | ((unsigned)f2bf(acc[mt][nt][3]) << 16);
                *(unsigned*)&Ps[q][key]     = p01;
                *(unsigned*)&Ps[q][key + 2] = p23;
            }
        if (l < 16) {
#pragma unroll
            for (int nt = 0; nt < 4; ++nt) red[w][16*nt + l] = sw[nt];
        }
        __syncthreads();
        float Lq[4];
#pragma unroll
        for (int nt = 0; nt < 4; ++nt) {
            float s = 0.f;
#pragma unroll
            for (int i = 0; i < 8; ++i) s += red[i][16*nt + c];
            Lq[nt] = s;
        }
        if (w == 0 && l < 16) {
#pragma unroll
            for (int nt = 0; nt < 4; ++nt) { Mf[16*nt + l] = Mq[nt]; Lf[16*nt + l] = Lq[nt]; }
        }
        __syncthreads();
    }

    // ---- ctx = P * V^T : wave w owns q-tile (w>>1) x d-tiles {w&1, (w&1)+2} ----
    int qt = w >> 1;
    int dt0 = (w & 1), dt1 = (w & 1) + 2;
    f32x4 pacc0 = (f32x4){0.f,0.f,0.f,0.f}, pacc1 = (f32x4){0.f,0.f,0.f,0.f};
    const unsigned short* VTp = VTb + (size_t)bh * DH * SLEN;
#pragma unroll
    for (int ks = 0; ks < 16; ++ks) {
        int blk2 = kb[ks >> 1];
        if (blk2 < 0) continue;
        bf16x8 pa = *(const bf16x8*)&Ps[16*qt + c][32*ks + 8*g];
        int skey = blk2 * 64 + ((ks & 1) ? 32 : 0) + 8*g;
        bf16x8 v0 = *(const bf16x8*)&VTp[(size_t)(16*dt0 + c) * SLEN + skey];
        bf16x8 v1 = *(const bf16x8*)&VTp[(size_t)(16*dt1 + c) * SLEN + skey];
        pacc0 = __builtin_amdgcn_mfma_f32_16x16x32_bf16(pa, v0, pacc0, 0, 0, 0);
        pacc1 = __builtin_amdgcn_mfma_f32_16x16x32_bf16(pa, v1, pacc1, 0, 0, 0);
    }

    if (mode == 0) {
#pragma unroll
        for (int j = 0; j < 2; ++j) {
            f32x4 pa = j ? pacc1 : pacc0;
            int dt = j ? dt1 : dt0;
#pragma unroll
            for (int r2 = 0; r2 < 4; ++r2) {
                int q = 16*qt + 4*g + r2;
                int d = 16*dt + c;
                int s = qb * 64 + q;
                float val = pa[r2] / Lf[q] * from_mask[b * SLEN + s];
                out[((size_t)b * SLEN + s) * HDIM + h * DH + d] = val;
            }
        }
    } else {
        float* pb = partials + (size_t)((bh * 2 + (qb == 63 ? 1 : 0)) * 8 + pslot) * 4224;
#pragma unroll
        for (int j = 0; j < 2; ++j) {
            f32x4 pa = j ? pacc1 : pacc0;
            int dt = j ? dt1 : dt0;
#pragma unroll
            for (int r2 = 0; r2 < 4; ++r2) {
                int q = 16*qt + 4*g + r2;
                int d = 16*dt + c;
                pb[q * 64 + d] = pa[r2];
            }
        }
        if (w == 0 && l < 16) {
#pragma unroll
            for (int nt = 0; nt < 4; ++nt) {
                pb[4096 + 16*nt + l] = Mf[16*nt + l];
                pb[4160 + 16*nt + l] = Lf[16*nt + l];
            }
        }
    }
}

// ---------------- combine 8 partials for row-blocks 0 and 63 ----------------
__global__ void k_combine(const float* __restrict__ partials, const float* __restrict__ from_mask,
                          float* __restrict__ out) {
    int gid = blockIdx.x;          // 48 = bh*2 + rb
    int bh = gid >> 1, rb = gid & 1;
    int b = bh / NHD, h = bh - b * NHD;
    int t = threadIdx.x;           // 256
    int q = t >> 2, dc = (t & 3) * 16;
    const float* base = partials + (size_t)gid * 8 * 4224;
    float M = -1e30f;
#pragma unroll
    for (int i = 0; i < 8; ++i) M = fmaxf(M, base[i*4224 + 4096 + q]);
    float L = 0.f, cx[16];
#pragma unroll
    for (int j = 0; j < 16; ++j) cx[j] = 0.f;
    for (int i = 0; i < 8; ++i) {
        float sc = __expf(base[i*4224 + 4096 + q] - M);
        L += base[i*4224 + 4160 + q] * sc;
#pragma unroll
        for (int j = 0; j < 16; ++j) cx[j] += base[i*4224 + q*64 + dc + j] * sc;
    }
    int s = (rb ? 4032 : 0) + q;
    float fm = from_mask[b * SLEN + s];
    float inv = fm / L;
#pragma unroll
    for (int j = 0; j < 16; ++j)
        out[((size_t)b * SLEN + s) * HDIM + h * DH + dc + j] = cx[j] * inv;
}

extern "C" void kernel_launch(void* const* d_in, const int* in_sizes, int n_in,
                              void* d_out, int out_size, void* d_ws, size_t ws_size,
                              hipStream_t stream) {
    const float* hs    = (const float*)d_in[0];
    const float* Wq    = (const float*)d_in[1];
    const float* Wk    = (const float*)d_in[2];
    const float* Wv    = (const float*)d_in[3];
    const float* band  = (const float*)d_in[4];
    const float* fromm = (const float*)d_in[5];
    const float* tom   = (const float*)d_in[6];
    const float* fbm   = (const float*)d_in[7];
    const float* tbm   = (const float*)d_in[8];
    const int*   ra    = (const int*)d_in[9];      // harness passes integers as int32
    float* out = (float*)d_out;

    // workspace layout (bytes):
    //  [0, 12.58M)  hsb  (bf16 hidden)  -> reused by vtb after proj
    //  [12.58M, 16.12M) wtb (3x768x768 bf16)
    //  [16.12M, 53.87M) qkv (3 x (B,NH,S,D) bf16)
    //  [53.87M, 60.36M) partials (48 x 8 x 4224 f32)
    char* ws = (char*)d_ws;
    unsigned short* hsb = (unsigned short*)(ws);
    unsigned short* vtb = (unsigned short*)(ws);                 // reuse (proj done before vtrans)
    unsigned short* wtb = (unsigned short*)(ws + 12582912);
    unsigned short* qkv = (unsigned short*)(ws + 16121856);
    float* partials     = (float*)(ws + 53870592);

    k_cast_hs<<<3072, 256, 0, stream>>>(hs, hsb, 786432);
    k_wt<<<dim3(12, 12, 3), 256, 0, stream>>>(Wq, Wk, Wv, wtb);
    k_proj<<<dim3(64, 6, 3), 256, 0, stream>>>(hsb, wtb, qkv);
    k_vtrans<<<dim3(64, 24), 256, 0, stream>>>(qkv + 2 * 6291456, vtb);
    k_attn<<<1872, 512, 0, stream>>>(qkv, qkv + 6291456, vtb, ra,
                                     band, fromm, tom, fbm, tbm, out, partials);
    k_combine<<<48, 256, 0, stream>>>(partials, fromm, out);
}